// Round 12
// baseline (143.058 us; speedup 1.0000x reference)
//
#include <hip/hip_runtime.h>

// MedianPool 17x17 stride 1, zero-padded SAME. Input (1,4,256,256) fp32.
//
// Round 12: batched multi-threshold selection (algorithmic probe reduction).
//   r11 post-mortem: VGPR 28->52 via waves_per_eu(4,4) made things WORSE
//   (85.6 vs 77.1 us; occ 60->33%) -- AGPR traffic is cheaper than lost
//   occupancy; residency is not the lever. Instrs/wave stuck at ~2400 across
//   r2/r6/r7/r11 with bit-identical LDS conflicts => cost is algorithmic:
//   ~15-16 wave-max adaptive probe iterations (divergent trip counts, branchy
//   mid selection) where ~7 probes' information suffices.
//   Fix: fixed-count batched probing.
//     Pass A: ONE scan counting 7 fixed Gaussian-quantile thresholds
//             {+-0.16,+-0.08,+-0.04,0} + (==0), packed 10-bit x3 per int;
//             gives the zero shortcut AND brackets the median into a cell
//             (sample median ~ N(0,0.074^2); expected 4-9 values in cell).
//     Pass B: ONE tri-section scan inside the cell -> usually <=2 left.
//     Fallback: r2's proven adaptive loop (rarely iterates; handles tails
//             where one side is +-INF, ties, degenerate brackets).
//   Counts are exact at every step -> invariant count(<lo)<=144<count(<hi)
//   holds throughout; extract identical to r2 (absmax 0 three times).
// Predicted: dur 77 -> 45-58 us; conflicts ~2.67M unchanged; occ ~60%.

#define RAD 8
#define TW 8
#define TH 4
#define PW (TW + 2 * RAD)   // 24
#define PH (TH + 2 * RAD)   // 20
#define LDSW 25             // padded LDS stride
#define MEDRANK 144         // 0-based rank of lower median (of 289)

__global__ __launch_bounds__(256, 4)
void median17_kernel(const float* __restrict__ x, float* __restrict__ out) {
    __shared__ float tile[PH * LDSW];

    const int tid = threadIdx.x;
    const int bid = blockIdx.x;
    // grid: 4 ch * 64 y-tiles * 32 x-tiles = 8192 blocks, 32 pixels/block
    const int c  = bid >> 11;
    const int t  = bid & 2047;
    const int oy = (t >> 5) * TH;
    const int ox = (t & 31) * TW;
    const float* xc = x + c * 65536;

    // stage 20x24 patch, zero padded
    for (int i = tid; i < PH * PW; i += 256) {
        int r   = i / PW;
        int col = i - r * PW;
        int gy  = oy - RAD + r;
        int gx  = ox - RAD + col;
        float v = 0.0f;
        if ((unsigned)gy < 256u && (unsigned)gx < 256u) v = xc[gy * 256 + gx];
        tile[r * LDSW + col] = v;
    }
    __syncthreads();

    const int j  = tid & 7;     // lane within octet (one pixel per 8 lanes)
    const int g  = tid >> 3;    // pixel 0..31
    const int py = g >> 3;
    const int px = g & 7;

    const float FINF = __builtin_inff();

    // lane j owns flat window indices [37j, 37j+37); f>=289 padded +INF.
    float w[37];
    {
        const int f0  = 37 * j;
        const int dy0 = f0 / 17;
        int dx = f0 - dy0 * 17;
        int a  = (py + dy0) * LDSW + px + dx;
#pragma unroll
        for (int k = 0; k < 37; ++k) {
            bool ok   = (k < 30) || (j < 7);     // f0+k < 289
            float v   = tile[ok ? a : 0];
            w[k]      = ok ? v : FINF;
            bool wrap = (dx == 16);
            a  += wrap ? (LDSW - 16) : 1;
            dx  = wrap ? 0 : dx + 1;
        }
    }

    // ---- Pass A: 7 fixed thresholds + zero count, ONE scan ----
    const float TA0 = -0.16f, TA1 = -0.08f, TA2 = -0.04f, TA3 = 0.0f,
                TA4 =  0.04f, TA5 =  0.08f, TA6 =  0.16f;
    int n0=0,n1=0,n2=0,n3=0,n4=0,n5=0,n6=0,nz=0;
#pragma unroll
    for (int k = 0; k < 37; ++k) {
        float v = w[k];
        n0 += (v < TA0); n1 += (v < TA1); n2 += (v < TA2); n3 += (v < TA3);
        n4 += (v < TA4); n5 += (v < TA5); n6 += (v < TA6); nz += (v == 0.0f);
    }
    // pack (per-lane <=37, octet total <=296 < 1024: no field overflow)
    int pA = n0 | (n1 << 10) | (n2 << 20);
    int pB = n3 | (n4 << 10) | (n5 << 20);
    int pC = n6 | (nz << 10);
    pA += __shfl_xor(pA,1); pA += __shfl_xor(pA,2); pA += __shfl_xor(pA,4);
    pB += __shfl_xor(pB,1); pB += __shfl_xor(pB,2); pB += __shfl_xor(pB,4);
    pC += __shfl_xor(pC,1); pC += __shfl_xor(pC,2); pC += __shfl_xor(pC,4);
    const int m0 = pA & 1023, m1 = (pA >> 10) & 1023, m2 = (pA >> 20) & 1023;
    const int m3 = pB & 1023, m4 = (pB >> 10) & 1023, m5 = (pB >> 20) & 1023;
    const int m6 = pC & 1023, cz = (pC >> 10) & 1023;
    const int c0 = m3;          // count(v < 0)

    float med;
    if (c0 <= MEDRANK && MEDRANK < c0 + cz) {
        // zero is the exact lower median (border pixels with padding dups)
        med = 0.0f;
    } else {
        float lo = -FINF, hi = FINF;
        int   lc = 0,     hc = 289;
        // lo = largest Ti with mi<=144 (ascending overwrite);
        // hi = smallest Ti with mi>144 (descending overwrite). Counts exact.
#define CL(T,N) { bool b = ((N) <= MEDRANK); lo = b ? (T) : lo; lc = b ? (N) : lc; }
#define CH(T,N) { bool b = ((N) >  MEDRANK); hi = b ? (T) : hi; hc = b ? (N) : hc; }
        CL(TA0,m0) CL(TA1,m1) CL(TA2,m2) CL(TA3,m3) CL(TA4,m4) CL(TA5,m5) CL(TA6,m6)
        CH(TA6,m6) CH(TA5,m5) CH(TA4,m4) CH(TA3,m3) CH(TA2,m2) CH(TA1,m1) CH(TA0,m0)

        // ---- Pass B: ONE tri-section scan when bracket finite & >2 ----
        if (hc - lc > 2) {
            float wd = hi - lo;
            if (wd < 1.0e37f) {          // both sides finite
                float t1 = lo + 0.25f * wd;
                float t2 = lo + 0.50f * wd;
                float t3 = lo + 0.75f * wd;
                int q1 = 0, q2 = 0, q3 = 0;
#pragma unroll
                for (int k = 0; k < 37; ++k) {
                    float v = w[k];
                    q1 += (v < t1); q2 += (v < t2); q3 += (v < t3);
                }
                int p = q1 | (q2 << 10) | (q3 << 20);
                p += __shfl_xor(p,1); p += __shfl_xor(p,2); p += __shfl_xor(p,4);
                int u1 = p & 1023, u2 = (p >> 10) & 1023, u3 = (p >> 20) & 1023;
                CL(t1,u1) CL(t2,u2) CL(t3,u3)
                CH(t3,u3) CH(t2,u2) CH(t1,u1)
            }
        }
#undef CL
#undef CH

        // ---- Fallback: adaptive loop (usually exits immediately) ----
        for (int it = 0; it < 100; ++it) {
            if (hc - lc <= 2) break;
            float mid;
            if (hi == FINF) {            // all Ti<=144 => lo=0.16; expand up
                mid = fminf(2.0f * lo, 3.0e38f);
            } else if (lo == -FINF) {    // all Ti>144 => hi=-0.16; expand down
                mid = fmaxf(2.0f * hi, -3.0e38f);
            } else if (it & 1) {         // regula falsi on counts, clamped
                float wd = hi - lo;
                float fr = (float)(MEDRANK - lc) + 0.5f;
                mid = lo + wd * (fr / (float)(hc - lc));
                mid = fminf(fmaxf(mid, lo + 0.03125f * wd), hi - 0.03125f * wd);
            } else {                     // safeguarded bisection
                mid = 0.5f * (lo + hi);
            }
            if (!(mid > lo && mid < hi)) {
                mid = 0.5f * (lo + hi);
                if (!(mid > lo && mid < hi)) break;  // <=2 representable left
            }
            int q = 0;
#pragma unroll
            for (int k = 0; k < 37; ++k) q += (w[k] < mid);
            q += __shfl_xor(q,1); q += __shfl_xor(q,2); q += __shfl_xor(q,4);
            if (q <= MEDRANK) { lo = mid; lc = q; }
            else              { hi = mid; hc = q; }
        }

        // extract rank rk (0 or 1) among values in [lo, hi).
        const int rk = MEDRANK - lc;
        float q0a = FINF, q1a = FINF, q0b = FINF, q1b = FINF;
#pragma unroll
        for (int k = 0; k < 37; k += 2) {
            {
                float v  = w[k];
                bool in  = (v >= lo) & (v < hi);
                float xv = in ? v : FINF;
                float t0 = fminf(q0a, xv);
                q1a = fminf(q1a, fmaxf(q0a, xv));
                q0a = t0;
            }
            if (k + 1 < 37) {
                float v  = w[k + 1];
                bool in  = (v >= lo) & (v < hi);
                float xv = in ? v : FINF;
                float t0 = fminf(q0b, xv);
                q1b = fminf(q1b, fmaxf(q0b, xv));
                q0b = t0;
            }
        }
        float s0 = fminf(q0a, q0b);
        float s1 = fminf(fminf(q1a, q1b), fmaxf(q0a, q0b));
#pragma unroll
        for (int d = 1; d <= 4; d <<= 1) {
            float r0 = __shfl_xor(s0, d);
            float r1 = __shfl_xor(s1, d);
            float n0f = fminf(s0, r0);
            float n1f = fminf(fminf(s1, r1), fmaxf(s0, r0));
            s0 = n0f; s1 = n1f;
        }
        med = (rk == 0) ? s0 : s1;
    }

    if (j == 0) {
        out[c * 65536 + (oy + py) * 256 + ox + px] = med;
    }
}

extern "C" void kernel_launch(void* const* d_in, const int* in_sizes, int n_in,
                              void* d_out, int out_size, void* d_ws, size_t ws_size,
                              hipStream_t stream) {
    const float* x = (const float*)d_in[0];
    float* out = (float*)d_out;
    median17_kernel<<<dim3(8192), dim3(256), 0, stream>>>(x, out);
}